// Round 1
// baseline (14213.506 us; speedup 1.0000x reference)
//
#include <hip/hip_runtime.h>
#include <hip/hip_bf16.h>

#define B_ 128
#define S_ 512
#define C_ 512
#define H_ 512
#define NC_ 64
#define T_ 25
#define TEXTW (T_ + 1)

// ---------------- zero init for h, c ----------------
__global__ void zero2(float* a, float* b, int n) {
    int i = blockIdx.x * blockDim.x + threadIdx.x;
    if (i < n) { a[i] = 0.f; b[i] = 0.f; }
}

// ---------------- proj = x @ W_i2h  (M=65536, K=512, N=512) ----------------
__global__ __launch_bounds__(256) void gemm_proj(const float* __restrict__ A,
                                                 const float* __restrict__ Bm,
                                                 float* __restrict__ Cm) {
    __shared__ float As[64][33];
    __shared__ float Bs[32][65];
    int tid = threadIdx.x;
    int tx = tid & 15, ty = tid >> 4;
    int row0 = blockIdx.y * 64;
    int col0 = blockIdx.x * 64;
    float acc[4][4] = {};
    for (int k0 = 0; k0 < 512; k0 += 32) {
#pragma unroll
        for (int i = 0; i < 8; ++i) {
            int e = tid + i * 256;
            int r = e >> 5, cc = e & 31;
            As[r][cc] = A[(size_t)(row0 + r) * 512 + k0 + cc];
        }
#pragma unroll
        for (int i = 0; i < 8; ++i) {
            int e = tid + i * 256;
            int r = e >> 6, cc = e & 63;
            Bs[r][cc] = Bm[(size_t)(k0 + r) * 512 + col0 + cc];
        }
        __syncthreads();
#pragma unroll
        for (int kk = 0; kk < 32; ++kk) {
            float a[4], bv[4];
#pragma unroll
            for (int i = 0; i < 4; ++i) a[i] = As[ty * 4 + i][kk];
#pragma unroll
            for (int j = 0; j < 4; ++j) bv[j] = Bs[kk][tx * 4 + j];
#pragma unroll
            for (int i = 0; i < 4; ++i)
#pragma unroll
                for (int j = 0; j < 4; ++j) acc[i][j] += a[i] * bv[j];
        }
        __syncthreads();
    }
#pragma unroll
    for (int i = 0; i < 4; ++i)
#pragma unroll
        for (int j = 0; j < 4; ++j)
            Cm[(size_t)(row0 + ty * 4 + i) * 512 + col0 + tx * 4 + j] = acc[i][j];
}

// ---------------- fused attention step: hp -> e -> softmax -> context ----------------
// one block per batch element b; 512 threads (8 waves)
__global__ __launch_bounds__(512) void attn_step(
    const float* __restrict__ proj, const float* __restrict__ x,
    const float* __restrict__ Wh2h, const float* __restrict__ bh2h,
    const float* __restrict__ Wscore, const float* __restrict__ h,
    float* __restrict__ context) {
    __shared__ float sh_h[H_];
    __shared__ float sh_hp[H_];
    __shared__ float sh_w[H_];
    __shared__ float sh_e[S_];
    __shared__ float sh_red[16];
    int tid = threadIdx.x;
    int b = blockIdx.x;
    sh_h[tid] = h[b * H_ + tid];
    sh_w[tid] = Wscore[tid];
    __syncthreads();
    // hp[j] = b_h2h[j] + sum_k h[k] * W_h2h[k, j]
    {
        float acc = bh2h[tid];
        for (int k = 0; k < H_; ++k) acc += sh_h[k] * Wh2h[k * H_ + tid];
        sh_hp[tid] = acc;
    }
    __syncthreads();
    // e[s] = sum_h tanh(proj[b,s,h] + hp[h]) * Wscore[h]
    int wave = tid >> 6, lane = tid & 63;
    for (int s = wave; s < S_; s += 8) {
        const float* p = proj + (size_t)(b * S_ + s) * H_;
        float a = 0.f;
#pragma unroll
        for (int j = 0; j < 8; ++j) {
            int hh = lane + 64 * j;
            a += tanhf(p[hh] + sh_hp[hh]) * sh_w[hh];
        }
#pragma unroll
        for (int off = 32; off > 0; off >>= 1) a += __shfl_xor(a, off, 64);
        if (lane == 0) sh_e[s] = a;
    }
    __syncthreads();
    // softmax over s (512 values, one per thread)
    float v = sh_e[tid];
    float m = v;
#pragma unroll
    for (int off = 32; off > 0; off >>= 1) m = fmaxf(m, __shfl_xor(m, off, 64));
    if (lane == 0) sh_red[wave] = m;
    __syncthreads();
    if (tid == 0) {
        float mm = sh_red[0];
        for (int i = 1; i < 8; ++i) mm = fmaxf(mm, sh_red[i]);
        sh_red[8] = mm;
    }
    __syncthreads();
    float p = expf(v - sh_red[8]);
    float ss = p;
#pragma unroll
    for (int off = 32; off > 0; off >>= 1) ss += __shfl_xor(ss, off, 64);
    __syncthreads();
    if (lane == 0) sh_red[wave] = ss;
    __syncthreads();
    if (tid == 0) {
        float tt = 0.f;
        for (int i = 0; i < 8; ++i) tt += sh_red[i];
        sh_red[9] = tt;
    }
    __syncthreads();
    sh_e[tid] = p / sh_red[9];
    __syncthreads();
    // context[c] = sum_s alpha[s] * x[b,s,c]
    {
        float acc = 0.f;
        for (int s = 0; s < S_; ++s) acc += sh_e[s] * x[(size_t)(b * S_ + s) * C_ + tid];
        context[b * C_ + tid] = acc;
    }
}

// ---------------- fused LSTM step: z = [ctx|onehot]@W + h@U + b; gates; h,c update ----------------
// grid 32 blocks of 512 threads; each block handles 4 batch rows; thread = one h-index, all 4 gates
__global__ __launch_bounds__(512) void lstm_step(
    const float* __restrict__ context, const float* __restrict__ h,
    const float* __restrict__ cst, const int* __restrict__ text,
    const float* __restrict__ Wl, const float* __restrict__ Ul,
    const float* __restrict__ bl,
    float* __restrict__ h_out, float* __restrict__ c_out,
    float* __restrict__ hs_t, int t) {
    __shared__ float sh_in[4][1024];  // [ctx(512) | h(512)] per b
    __shared__ int sh_char[4];
    int tid = threadIdx.x;
    int b0 = blockIdx.x * 4;
#pragma unroll
    for (int i = 0; i < 8; ++i) {
        int e = tid + i * 512;
        int bb = e >> 10, k = e & 1023;
        sh_in[bb][k] = (k < 512) ? context[(b0 + bb) * 512 + k]
                                 : h[(b0 + bb) * 512 + (k - 512)];
    }
    if (tid < 4) sh_char[tid] = text[(b0 + tid) * TEXTW + t];
    __syncthreads();
    int hh = tid;
    float acc0[4], acc1[4], acc2[4], acc3[4];
    {
        float bi = bl[hh], bf = bl[512 + hh], bg = bl[1024 + hh], bo = bl[1536 + hh];
#pragma unroll
        for (int bb = 0; bb < 4; ++bb) { acc0[bb] = bi; acc1[bb] = bf; acc2[bb] = bg; acc3[bb] = bo; }
    }
    for (int k = 0; k < 512; ++k) {
        float w0 = Wl[(size_t)k * 2048 + hh];
        float w1 = Wl[(size_t)k * 2048 + 512 + hh];
        float w2 = Wl[(size_t)k * 2048 + 1024 + hh];
        float w3 = Wl[(size_t)k * 2048 + 1536 + hh];
        float u0 = Ul[(size_t)k * 2048 + hh];
        float u1 = Ul[(size_t)k * 2048 + 512 + hh];
        float u2 = Ul[(size_t)k * 2048 + 1024 + hh];
        float u3 = Ul[(size_t)k * 2048 + 1536 + hh];
#pragma unroll
        for (int bb = 0; bb < 4; ++bb) {
            float cv = sh_in[bb][k], hv = sh_in[bb][512 + k];
            acc0[bb] += cv * w0 + hv * u0;
            acc1[bb] += cv * w1 + hv * u1;
            acc2[bb] += cv * w2 + hv * u2;
            acc3[bb] += cv * w3 + hv * u3;
        }
    }
#pragma unroll
    for (int bb = 0; bb < 4; ++bb) {
        const float* wrow = Wl + (size_t)(512 + sh_char[bb]) * 2048;
        float zi = acc0[bb] + wrow[hh];
        float zf = acc1[bb] + wrow[512 + hh];
        float zg = acc2[bb] + wrow[1024 + hh];
        float zo = acc3[bb] + wrow[1536 + hh];
        float ig = 1.f / (1.f + expf(-zi));
        float fg = 1.f / (1.f + expf(-zf));
        float gg = tanhf(zg);
        float og = 1.f / (1.f + expf(-zo));
        int idx = (b0 + bb) * 512 + hh;
        float cn = fg * cst[idx] + ig * gg;
        float hn = og * tanhf(cn);
        c_out[idx] = cn;
        h_out[idx] = hn;
        hs_t[idx] = hn;
    }
}

// ---------------- probs = hs @ W_gen + b_gen ----------------
__global__ __launch_bounds__(64) void gen_probs(const float* __restrict__ hs,
                                                const float* __restrict__ Wg,
                                                const float* __restrict__ bg,
                                                float* __restrict__ out) {
    __shared__ float sh[512];
    int bt = blockIdx.x;  // b*T + t
    int b = bt / T_, t = bt % T_;
    int tid = threadIdx.x;
    const float* hrow = hs + ((size_t)t * B_ + b) * H_;
    for (int i = tid; i < 512; i += 64) sh[i] = hrow[i];
    __syncthreads();
    float acc = bg[tid];
    for (int k = 0; k < 512; ++k) acc += sh[k] * Wg[k * 64 + tid];
    out[(size_t)bt * 64 + tid] = acc;
}

extern "C" void kernel_launch(void* const* d_in, const int* in_sizes, int n_in,
                              void* d_out, int out_size, void* d_ws, size_t ws_size,
                              hipStream_t stream) {
    const float* x       = (const float*)d_in[0];
    const int*   text    = (const int*)d_in[1];
    const float* W_i2h   = (const float*)d_in[2];
    const float* W_h2h   = (const float*)d_in[3];
    const float* b_h2h   = (const float*)d_in[4];
    const float* W_score = (const float*)d_in[5];
    const float* W_lstm  = (const float*)d_in[6];
    const float* U_lstm  = (const float*)d_in[7];
    const float* b_lstm  = (const float*)d_in[8];
    const float* W_gen   = (const float*)d_in[9];
    const float* b_gen   = (const float*)d_in[10];
    float* out = (float*)d_out;

    char* ws = (char*)d_ws;
    float* proj    = (float*)ws;                            // 128*512*512 f32 = 134 MB
    float* h       = (float*)(ws + (size_t)134217728);      // 65536
    float* c       = h + 65536;
    float* context = c + 65536;
    float* hs      = context + 65536;                       // 25*128*512

    zero2<<<dim3(128), 512, 0, stream>>>(h, c, 65536);
    gemm_proj<<<dim3(8, 1024), 256, 0, stream>>>(x, W_i2h, proj);
    for (int t = 0; t < T_; ++t) {
        attn_step<<<dim3(B_), 512, 0, stream>>>(proj, x, W_h2h, b_h2h, W_score, h, context);
        lstm_step<<<dim3(32), 512, 0, stream>>>(context, h, c, text, W_lstm, U_lstm, b_lstm,
                                                h, c, hs + (size_t)t * (B_ * H_), t);
    }
    gen_probs<<<dim3(B_ * T_), 64, 0, stream>>>(hs, W_gen, b_gen, out);
}

// Round 2
// 6211.537 us; speedup vs baseline: 2.2882x; 2.2882x over previous
//
#include <hip/hip_runtime.h>
#include <hip/hip_bf16.h>

#define B_ 128
#define S_ 512
#define C_ 512
#define H_ 512
#define NC_ 64
#define T_ 25
#define TEXTW (T_ + 1)

typedef __attribute__((ext_vector_type(8))) short bf16x8;
typedef __attribute__((ext_vector_type(4))) float f32x4;

__device__ __forceinline__ float bf2f(unsigned short u) {
    union { unsigned int i; float f; } v; v.i = ((unsigned int)u) << 16; return v.f;
}
__device__ __forceinline__ unsigned short f2bf(float f) {
    union { float f; unsigned int u; } v; v.f = f;
    unsigned int r = (v.u + 0x7FFFu + ((v.u >> 16) & 1u)) >> 16;
    return (unsigned short)r;
}
__device__ __forceinline__ void gload_lds16(const void* g, void* l) {
    __builtin_amdgcn_global_load_lds(
        (const __attribute__((address_space(1))) unsigned int*)g,
        (__attribute__((address_space(3))) unsigned int*)l, 16, 0, 0);
}

// ---------------- init h, c ----------------
__global__ void zero2(float* a, float* b, int n) {
    int i = blockIdx.x * blockDim.x + threadIdx.x;
    if (i < n) { a[i] = 0.f; b[i] = 0.f; }
}

// ---------------- conversions ----------------
// x f32 [65536,512] -> bf16 same layout
__global__ __launch_bounds__(256) void conv_x(const float* __restrict__ in,
                                              unsigned short* __restrict__ out) {
    int i = blockIdx.x * 256 + threadIdx.x;  // float4 index
    const float4 v = ((const float4*)in)[i];
    ushort4 o;
    o.x = f2bf(v.x); o.y = f2bf(v.y); o.z = f2bf(v.z); o.w = f2bf(v.w);
    ((ushort4*)out)[i] = o;
}

// W_i2h [k=512][n=512] f32 -> Wt_bf [n][k] bf16 (transpose)
__global__ __launch_bounds__(512) void conv_wt(const float* __restrict__ in,
                                               unsigned short* __restrict__ out) {
    int n = blockIdx.x;
    int k = threadIdx.x;
    out[n * 512 + k] = f2bf(in[k * 512 + n]);
}

// W_h2h f32 -> bf16 same layout
__global__ __launch_bounds__(512) void conv_wh(const float* __restrict__ in,
                                               unsigned short* __restrict__ out) {
    int i = blockIdx.x * 512 + threadIdx.x;
    out[i] = f2bf(in[i]);
}

// W_lstm[:512] stacked with U_lstm -> WU_g [k=1024][h=512][g=4] bf16 (gate-interleaved)
__global__ __launch_bounds__(256) void conv_wu(const float* __restrict__ W,
                                               const float* __restrict__ U,
                                               unsigned short* __restrict__ out) {
    int gidx = blockIdx.x * 256 + threadIdx.x;  // [0, 1024*512)
    int k = gidx >> 9, h = gidx & 511;
    const float* src = (k < 512) ? (W + (size_t)k * 2048) : (U + (size_t)(k - 512) * 2048);
    ushort4 o;
    o.x = f2bf(src[h]);
    o.y = f2bf(src[512 + h]);
    o.z = f2bf(src[1024 + h]);
    o.w = f2bf(src[1536 + h]);
    ((ushort4*)(out + (size_t)k * 2048 + h * 4))[0] = o;
}

// ---------------- proj = x @ W_i2h via MFMA, bf16 in/out ----------------
// 128x128 tile, BK=64, 256 threads (4 waves, 2x2 wave grid of 64x64), XOR-swizzled LDS
__global__ __launch_bounds__(256) void gemm_proj(const unsigned short* __restrict__ A,
                                                 const unsigned short* __restrict__ Bt,
                                                 unsigned short* __restrict__ Cm) {
    __shared__ unsigned short As[128 * 64];  // [row][8 chunks of 8 bf16], chunk-swizzled
    __shared__ unsigned short Bs[128 * 64];
    int tid = threadIdx.x;
    int lane = tid & 63;
    int wid = tid >> 6;
    int wr = wid >> 1, wc = wid & 1;
    int row0 = blockIdx.y * 128;
    int col0 = blockIdx.x * 128;

    f32x4 acc[4][4];
#pragma unroll
    for (int i = 0; i < 4; ++i)
#pragma unroll
        for (int j = 0; j < 4; ++j) acc[i][j] = (f32x4){0.f, 0.f, 0.f, 0.f};

    for (int k0 = 0; k0 < 512; k0 += 64) {
#pragma unroll
        for (int i = 0; i < 4; ++i) {
            int e = tid + i * 256;            // chunk id [0,1024)
            int r = e >> 3, cc = e & 7;
            int cs = cc ^ (r & 7);            // pre-swizzled global source chunk
            gload_lds16(A + (size_t)(row0 + r) * 512 + k0 + cs * 8, &As[e * 8]);
        }
#pragma unroll
        for (int i = 0; i < 4; ++i) {
            int e = tid + i * 256;
            int r = e >> 3, cc = e & 7;
            int cs = cc ^ (r & 7);
            gload_lds16(Bt + (size_t)(col0 + r) * 512 + k0 + cs * 8, &Bs[e * 8]);
        }
        __syncthreads();
#pragma unroll
        for (int ks = 0; ks < 2; ++ks) {
            bf16x8 a[4], b[4];
#pragma unroll
            for (int i = 0; i < 4; ++i) {
                int m = wr * 64 + i * 16 + (lane & 15);
                int ch = (ks * 4 + (lane >> 4)) ^ (m & 7);
                a[i] = *(const bf16x8*)&As[(m * 8 + ch) * 8];
            }
#pragma unroll
            for (int j = 0; j < 4; ++j) {
                int n = wc * 64 + j * 16 + (lane & 15);
                int ch = (ks * 4 + (lane >> 4)) ^ (n & 7);
                b[j] = *(const bf16x8*)&Bs[(n * 8 + ch) * 8];
            }
#pragma unroll
            for (int i = 0; i < 4; ++i)
#pragma unroll
                for (int j = 0; j < 4; ++j)
                    acc[i][j] = __builtin_amdgcn_mfma_f32_16x16x32_bf16(a[i], b[j], acc[i][j], 0, 0, 0);
        }
        __syncthreads();
    }
#pragma unroll
    for (int i = 0; i < 4; ++i)
#pragma unroll
        for (int j = 0; j < 4; ++j) {
            int gcol = col0 + wc * 64 + j * 16 + (lane & 15);
#pragma unroll
            for (int r = 0; r < 4; ++r) {
                int grow = row0 + wr * 64 + i * 16 + (lane >> 4) * 4 + r;
                Cm[(size_t)grow * 512 + gcol] = f2bf(acc[i][j][r]);
            }
        }
}

// ---------------- fused attention step ----------------
// one block per batch element; 512 threads (8 waves)
__global__ __launch_bounds__(512) void attn_step(
    const unsigned short* __restrict__ proj, const unsigned short* __restrict__ xb,
    const unsigned short* __restrict__ Whb, const float* __restrict__ bh2h,
    const float* __restrict__ Wscore, const float* __restrict__ h,
    float* __restrict__ context) {
    __shared__ float sh_h[H_];
    __shared__ float sh_hp[H_];
    __shared__ float sh_e[S_];
    __shared__ float sh_red[16];
    int tid = threadIdx.x;
    int b = blockIdx.x;
    int wave = tid >> 6, lane = tid & 63;
    sh_h[tid] = h[b * H_ + tid];
    __syncthreads();
    // hp[j] = b_h2h[j] + sum_k h[k] * W_h2h[k, j]
    {
        float acc = bh2h[tid];
#pragma unroll 4
        for (int k = 0; k < H_; ++k) acc += sh_h[k] * bf2f(Whb[k * H_ + tid]);
        sh_hp[tid] = acc;
    }
    __syncthreads();
    // hoist hp and W_score for this lane's 8 h-values into registers
    float hp_r[8], w_r[8];
#pragma unroll
    for (int j = 0; j < 8; ++j) {
        hp_r[j] = sh_hp[lane * 8 + j];
        w_r[j] = Wscore[lane * 8 + j];
    }
    // e[s] = sum_h tanh(proj[b,s,h] + hp[h]) * Wscore[h]
    for (int s = wave; s < S_; s += 8) {
        const bf16x8 pv = *(const bf16x8*)(proj + ((size_t)(b * S_ + s) << 9) + lane * 8);
        float a = 0.f;
#pragma unroll
        for (int j = 0; j < 8; ++j)
            a += tanhf(bf2f((unsigned short)pv[j]) + hp_r[j]) * w_r[j];
#pragma unroll
        for (int off = 32; off > 0; off >>= 1) a += __shfl_xor(a, off, 64);
        if (lane == 0) sh_e[s] = a;
    }
    __syncthreads();
    // softmax over s
    float v = sh_e[tid];
    float m = v;
#pragma unroll
    for (int off = 32; off > 0; off >>= 1) m = fmaxf(m, __shfl_xor(m, off, 64));
    if (lane == 0) sh_red[wave] = m;
    __syncthreads();
    if (tid == 0) {
        float mm = sh_red[0];
        for (int i = 1; i < 8; ++i) mm = fmaxf(mm, sh_red[i]);
        sh_red[8] = mm;
    }
    __syncthreads();
    float p = expf(v - sh_red[8]);
    float ss = p;
#pragma unroll
    for (int off = 32; off > 0; off >>= 1) ss += __shfl_xor(ss, off, 64);
    if (lane == 0) sh_red[wave] = ss;
    __syncthreads();
    if (tid == 0) {
        float tt = 0.f;
        for (int i = 0; i < 8; ++i) tt += sh_red[i];
        sh_red[9] = tt;
    }
    __syncthreads();
    sh_e[tid] = p / sh_red[9];
    __syncthreads();
    // context[c] = sum_s alpha[s] * x[b,s,c]
    {
        float acc = 0.f;
#pragma unroll 4
        for (int s = 0; s < S_; ++s)
            acc += sh_e[s] * bf2f(xb[((size_t)(b * S_ + s) << 9) + tid]);
        context[b * C_ + tid] = acc;
    }
}

// ---------------- fused LSTM step ----------------
// 128 blocks (one per b) x 512 threads (thread = h index, all 4 gates)
__global__ __launch_bounds__(512) void lstm_step(
    const float* __restrict__ context, const float* __restrict__ h,
    const float* __restrict__ cst, const int* __restrict__ text,
    const unsigned short* __restrict__ WUg, const float* __restrict__ Wl,
    const float* __restrict__ bl,
    float* __restrict__ h_out, float* __restrict__ c_out,
    float* __restrict__ hs_t, int t) {
    __shared__ float sin_[1024];
    int tid = threadIdx.x;
    int b = blockIdx.x;
    sin_[tid] = context[b * 512 + tid];
    sin_[512 + tid] = h[b * 512 + tid];
    __syncthreads();
    int ch = text[b * TEXTW + t];
    const float* wrow = Wl + (size_t)(512 + ch) * 2048;
    float ai = bl[tid] + wrow[tid];
    float af = bl[512 + tid] + wrow[512 + tid];
    float ag = bl[1024 + tid] + wrow[1024 + tid];
    float ao = bl[1536 + tid] + wrow[1536 + tid];
#pragma unroll 4
    for (int k = 0; k < 1024; ++k) {
        float v = sin_[k];
        ushort4 w = *(const ushort4*)(WUg + (size_t)k * 2048 + tid * 4);
        ai += v * bf2f(w.x);
        af += v * bf2f(w.y);
        ag += v * bf2f(w.z);
        ao += v * bf2f(w.w);
    }
    float ig = 1.f / (1.f + expf(-ai));
    float fg = 1.f / (1.f + expf(-af));
    float gg = tanhf(ag);
    float og = 1.f / (1.f + expf(-ao));
    int idx = b * 512 + tid;
    float cn = fg * cst[idx] + ig * gg;
    float hn = og * tanhf(cn);
    c_out[idx] = cn;
    h_out[idx] = hn;
    hs_t[idx] = hn;
}

// ---------------- probs = hs @ W_gen + b_gen ----------------
__global__ __launch_bounds__(64) void gen_probs(const float* __restrict__ hs,
                                                const float* __restrict__ Wg,
                                                const float* __restrict__ bg,
                                                float* __restrict__ out) {
    __shared__ float sh[512];
    int bt = blockIdx.x;  // b*T + t
    int b = bt / T_, t = bt % T_;
    int tid = threadIdx.x;
    const float* hrow = hs + ((size_t)t * B_ + b) * H_;
    for (int i = tid; i < 512; i += 64) sh[i] = hrow[i];
    __syncthreads();
    float acc = bg[tid];
#pragma unroll 4
    for (int k = 0; k < 512; ++k) acc += sh[k] * Wg[k * 64 + tid];
    out[(size_t)bt * 64 + tid] = acc;
}

extern "C" void kernel_launch(void* const* d_in, const int* in_sizes, int n_in,
                              void* d_out, int out_size, void* d_ws, size_t ws_size,
                              hipStream_t stream) {
    const float* x       = (const float*)d_in[0];
    const int*   text    = (const int*)d_in[1];
    const float* W_i2h   = (const float*)d_in[2];
    const float* W_h2h   = (const float*)d_in[3];
    const float* b_h2h   = (const float*)d_in[4];
    const float* W_score = (const float*)d_in[5];
    const float* W_lstm  = (const float*)d_in[6];
    const float* U_lstm  = (const float*)d_in[7];
    const float* b_lstm  = (const float*)d_in[8];
    const float* W_gen   = (const float*)d_in[9];
    const float* b_gen   = (const float*)d_in[10];
    float* out = (float*)d_out;

    char* ws = (char*)d_ws;
    unsigned short* x_bf    = (unsigned short*)ws;                       // 67,108,864 B
    unsigned short* proj_bf = (unsigned short*)(ws + 67108864);          // 67,108,864 B
    unsigned short* Wt_bf   = (unsigned short*)(ws + 134217728);         // 524,288 B
    unsigned short* Wh_bf   = (unsigned short*)(ws + 134742016);         // 524,288 B
    unsigned short* WU_g    = (unsigned short*)(ws + 135266304);         // 4,194,304 B
    float* h       = (float*)(ws + 139460608);
    float* c       = (float*)(ws + 139722752);
    float* context = (float*)(ws + 139984896);
    float* hs      = (float*)(ws + 140247040);                           // 13,107,200 B

    zero2<<<dim3(128), 512, 0, stream>>>(h, c, 65536);
    conv_x<<<dim3(32768), 256, 0, stream>>>(x, x_bf);          // 8,388,608 float4s
    conv_wt<<<dim3(512), 512, 0, stream>>>(W_i2h, Wt_bf);
    conv_wh<<<dim3(512), 512, 0, stream>>>(W_h2h, Wh_bf);
    conv_wu<<<dim3(2048), 256, 0, stream>>>(W_lstm, U_lstm, WU_g);
    gemm_proj<<<dim3(4, 512), 256, 0, stream>>>(x_bf, Wt_bf, proj_bf);
    for (int t = 0; t < T_; ++t) {
        attn_step<<<dim3(B_), 512, 0, stream>>>(proj_bf, x_bf, Wh_bf, b_h2h, W_score, h, context);
        lstm_step<<<dim3(B_), 512, 0, stream>>>(context, h, c, text, WU_g, W_lstm, b_lstm,
                                                h, c, hs + (size_t)t * (B_ * H_), t);
    }
    gen_probs<<<dim3(B_ * T_), 64, 0, stream>>>(hs, W_gen, b_gen, out);
}

// Round 3
// 1900.952 us; speedup vs baseline: 7.4770x; 3.2676x over previous
//
#include <hip/hip_runtime.h>
#include <hip/hip_bf16.h>

#define B_ 128
#define S_ 512
#define C_ 512
#define H_ 512
#define NC_ 64
#define T_ 25
#define TEXTW (T_ + 1)

typedef __attribute__((ext_vector_type(8))) short bf16x8;
typedef __attribute__((ext_vector_type(4))) float f32x4;

__device__ __forceinline__ float bf2f(unsigned short u) {
    union { unsigned int i; float f; } v; v.i = ((unsigned int)u) << 16; return v.f;
}
__device__ __forceinline__ unsigned short f2bf(float f) {
    union { float f; unsigned int u; } v; v.f = f;
    unsigned int r = (v.u + 0x7FFFu + ((v.u >> 16) & 1u)) >> 16;
    return (unsigned short)r;
}
__device__ __forceinline__ void gload_lds16(const void* g, void* l) {
    __builtin_amdgcn_global_load_lds(
        (const __attribute__((address_space(1))) unsigned int*)g,
        (__attribute__((address_space(3))) unsigned int*)l, 16, 0, 0);
}
__device__ __forceinline__ float fast_tanh(float x) {
    float a = fabsf(x);
    float e = __builtin_amdgcn_exp2f(2.885390082f * a);  // e^{2|x|}
    float r = 1.f - 2.f * __builtin_amdgcn_rcpf(e + 1.f);
    return copysignf(r, x);
}
__device__ __forceinline__ float fast_sigmoid(float x) {
    return __builtin_amdgcn_rcpf(1.f + __builtin_amdgcn_exp2f(-1.442695041f * x));
}

// ---------------- init: h=c=0, hp=b_h2h, inp h-part = 0 ----------------
__global__ __launch_bounds__(512) void init_k(float* h, float* c, float* hp,
                                              const float* __restrict__ bh,
                                              unsigned short* inp) {
    int b = blockIdx.x, j = threadIdx.x;
    h[b * 512 + j] = 0.f;
    c[b * 512 + j] = 0.f;
    hp[b * 512 + j] = bh[j];
    inp[b * 1024 + 512 + j] = 0;
}

// ---------------- conversions ----------------
__global__ __launch_bounds__(256) void conv_x(const float* __restrict__ in,
                                              unsigned short* __restrict__ out) {
    int i = blockIdx.x * 256 + threadIdx.x;
    const float4 v = ((const float4*)in)[i];
    ushort4 o;
    o.x = f2bf(v.x); o.y = f2bf(v.y); o.z = f2bf(v.z); o.w = f2bf(v.w);
    ((ushort4*)out)[i] = o;
}

// W_i2h [k][n] -> [n][k] bf16
__global__ __launch_bounds__(512) void conv_wt(const float* __restrict__ in,
                                               unsigned short* __restrict__ out) {
    int n = blockIdx.x, k = threadIdx.x;
    out[n * 512 + k] = f2bf(in[k * 512 + n]);
}

// W_h2h -> bf16 same layout
__global__ __launch_bounds__(512) void conv_wh(const float* __restrict__ in,
                                               unsigned short* __restrict__ out) {
    int i = blockIdx.x * 512 + threadIdx.x;
    out[i] = f2bf(in[i]);
}

// WU_t [n'=h*4+g][k=1024] bf16  (B^T for the z-GEMM)
__global__ __launch_bounds__(256) void conv_wut(const float* __restrict__ W,
                                                const float* __restrict__ U,
                                                unsigned short* __restrict__ out) {
    int np = blockIdx.x;               // 2048
    int h = np >> 2, g = np & 3;
    for (int k = threadIdx.x; k < 1024; k += 256) {
        float v = (k < 512) ? W[(size_t)k * 2048 + g * 512 + h]
                            : U[(size_t)(k - 512) * 2048 + g * 512 + h];
        out[(size_t)np * 1024 + k] = f2bf(v);
    }
}

// ---------------- proj = x @ W_i2h via MFMA (bf16) ----------------
__global__ __launch_bounds__(256) void gemm_proj(const unsigned short* __restrict__ A,
                                                 const unsigned short* __restrict__ Bt,
                                                 unsigned short* __restrict__ Cm) {
    __shared__ unsigned short As[128 * 64];
    __shared__ unsigned short Bs[128 * 64];
    int tid = threadIdx.x;
    int lane = tid & 63;
    int wid = tid >> 6;
    int wr = wid >> 1, wc = wid & 1;
    int row0 = blockIdx.y * 128;
    int col0 = blockIdx.x * 128;

    f32x4 acc[4][4];
#pragma unroll
    for (int i = 0; i < 4; ++i)
#pragma unroll
        for (int j = 0; j < 4; ++j) acc[i][j] = (f32x4){0.f, 0.f, 0.f, 0.f};

    for (int k0 = 0; k0 < 512; k0 += 64) {
#pragma unroll
        for (int i = 0; i < 4; ++i) {
            int e = tid + i * 256;
            int r = e >> 3, cc = e & 7;
            int cs = cc ^ (r & 7);
            gload_lds16(A + (size_t)(row0 + r) * 512 + k0 + cs * 8, &As[e * 8]);
        }
#pragma unroll
        for (int i = 0; i < 4; ++i) {
            int e = tid + i * 256;
            int r = e >> 3, cc = e & 7;
            int cs = cc ^ (r & 7);
            gload_lds16(Bt + (size_t)(col0 + r) * 512 + k0 + cs * 8, &Bs[e * 8]);
        }
        __syncthreads();
#pragma unroll
        for (int ks = 0; ks < 2; ++ks) {
            bf16x8 a[4], b[4];
#pragma unroll
            for (int i = 0; i < 4; ++i) {
                int m = wr * 64 + i * 16 + (lane & 15);
                int ch = (ks * 4 + (lane >> 4)) ^ (m & 7);
                a[i] = *(const bf16x8*)&As[(m * 8 + ch) * 8];
            }
#pragma unroll
            for (int j = 0; j < 4; ++j) {
                int n = wc * 64 + j * 16 + (lane & 15);
                int ch = (ks * 4 + (lane >> 4)) ^ (n & 7);
                b[j] = *(const bf16x8*)&Bs[(n * 8 + ch) * 8];
            }
#pragma unroll
            for (int i = 0; i < 4; ++i)
#pragma unroll
                for (int j = 0; j < 4; ++j)
                    acc[i][j] = __builtin_amdgcn_mfma_f32_16x16x32_bf16(a[i], b[j], acc[i][j], 0, 0, 0);
        }
        __syncthreads();
    }
#pragma unroll
    for (int i = 0; i < 4; ++i)
#pragma unroll
        for (int j = 0; j < 4; ++j) {
            int gcol = col0 + wc * 64 + j * 16 + (lane & 15);
#pragma unroll
            for (int r = 0; r < 4; ++r) {
                int grow = row0 + wr * 64 + i * 16 + (lane >> 4) * 4 + r;
                Cm[(size_t)grow * 512 + gcol] = f2bf(acc[i][j][r]);
            }
        }
}

// ---------------- z = inp @ WU_t^T  (M=128, N'=2048, K=1024) ----------------
__global__ __launch_bounds__(256) void z_gemm(const unsigned short* __restrict__ A,
                                              const unsigned short* __restrict__ Bt,
                                              float* __restrict__ Z) {
    __shared__ unsigned short As[128 * 64];
    __shared__ unsigned short Bs[128 * 64];
    int tid = threadIdx.x;
    int lane = tid & 63;
    int wid = tid >> 6;
    int wr = wid >> 1, wc = wid & 1;
    int col0 = blockIdx.x * 128;

    f32x4 acc[4][4];
#pragma unroll
    for (int i = 0; i < 4; ++i)
#pragma unroll
        for (int j = 0; j < 4; ++j) acc[i][j] = (f32x4){0.f, 0.f, 0.f, 0.f};

    for (int k0 = 0; k0 < 1024; k0 += 64) {
#pragma unroll
        for (int i = 0; i < 4; ++i) {
            int e = tid + i * 256;
            int r = e >> 3, cc = e & 7;
            int cs = cc ^ (r & 7);
            gload_lds16(A + (size_t)r * 1024 + k0 + cs * 8, &As[e * 8]);
        }
#pragma unroll
        for (int i = 0; i < 4; ++i) {
            int e = tid + i * 256;
            int r = e >> 3, cc = e & 7;
            int cs = cc ^ (r & 7);
            gload_lds16(Bt + (size_t)(col0 + r) * 1024 + k0 + cs * 8, &Bs[e * 8]);
        }
        __syncthreads();
#pragma unroll
        for (int ks = 0; ks < 2; ++ks) {
            bf16x8 a[4], b[4];
#pragma unroll
            for (int i = 0; i < 4; ++i) {
                int m = wr * 64 + i * 16 + (lane & 15);
                int ch = (ks * 4 + (lane >> 4)) ^ (m & 7);
                a[i] = *(const bf16x8*)&As[(m * 8 + ch) * 8];
            }
#pragma unroll
            for (int j = 0; j < 4; ++j) {
                int n = wc * 64 + j * 16 + (lane & 15);
                int ch = (ks * 4 + (lane >> 4)) ^ (n & 7);
                b[j] = *(const bf16x8*)&Bs[(n * 8 + ch) * 8];
            }
#pragma unroll
            for (int i = 0; i < 4; ++i)
#pragma unroll
                for (int j = 0; j < 4; ++j)
                    acc[i][j] = __builtin_amdgcn_mfma_f32_16x16x32_bf16(a[i], b[j], acc[i][j], 0, 0, 0);
        }
        __syncthreads();
    }
#pragma unroll
    for (int i = 0; i < 4; ++i)
#pragma unroll
        for (int j = 0; j < 4; ++j) {
            int gcol = col0 + wc * 64 + j * 16 + (lane & 15);
#pragma unroll
            for (int r = 0; r < 4; ++r) {
                int grow = wr * 64 + i * 16 + (lane >> 4) * 4 + r;
                Z[(size_t)grow * 2048 + gcol] = acc[i][j][r];
            }
        }
}

// ---------------- e[b,s] = tanh(proj[b,s,:]+hp[b,:]) . Wscore ----------------
// grid (sc=8, b=128), 256 threads
__global__ __launch_bounds__(256) void e_kernel(
    const unsigned short* __restrict__ proj, const float* __restrict__ hp,
    const float* __restrict__ Wscore, float* __restrict__ e_buf) {
    int b = blockIdx.y, sc = blockIdx.x;
    int tid = threadIdx.x, wave = tid >> 6, lane = tid & 63;
    float4 h0 = *(const float4*)(hp + b * 512 + lane * 8);
    float4 h1 = *(const float4*)(hp + b * 512 + lane * 8 + 4);
    float4 w0 = *(const float4*)(Wscore + lane * 8);
    float4 w1 = *(const float4*)(Wscore + lane * 8 + 4);
    float hp_r[8] = {h0.x, h0.y, h0.z, h0.w, h1.x, h1.y, h1.z, h1.w};
    float w_r[8]  = {w0.x, w0.y, w0.z, w0.w, w1.x, w1.y, w1.z, w1.w};
    int s0 = sc * 64 + wave * 16;
    for (int i = 0; i < 16; ++i) {
        int s = s0 + i;
        const bf16x8 pv = *(const bf16x8*)(proj + ((size_t)(b * 512 + s) << 9) + lane * 8);
        float a = 0.f;
#pragma unroll
        for (int j = 0; j < 8; ++j)
            a += fast_tanh(bf2f((unsigned short)pv[j]) + hp_r[j]) * w_r[j];
#pragma unroll
        for (int off = 32; off > 0; off >>= 1) a += __shfl_xor(a, off, 64);
        if (lane == 0) e_buf[b * 512 + s] = a;
    }
}

// ---------------- softmax(e) + context -> inp_bf[b][0..512) ----------------
// grid (cc=4, b=128), 512 threads
__global__ __launch_bounds__(512) void ctx_kernel(
    const float* __restrict__ e_buf, const unsigned short* __restrict__ xb,
    unsigned short* __restrict__ inp) {
    __shared__ float sh_alpha[512];
    __shared__ float sh_red[16];
    __shared__ float2 shp[8][64];
    int b = blockIdx.y, cc = blockIdx.x;
    int tid = threadIdx.x, wave = tid >> 6, lane = tid & 63;
    float v = e_buf[b * 512 + tid];
    float m = v;
#pragma unroll
    for (int off = 32; off > 0; off >>= 1) m = fmaxf(m, __shfl_xor(m, off, 64));
    if (lane == 0) sh_red[wave] = m;
    __syncthreads();
    float mm = sh_red[0];
#pragma unroll
    for (int i = 1; i < 8; ++i) mm = fmaxf(mm, sh_red[i]);
    float p = __builtin_amdgcn_exp2f(1.442695041f * (v - mm));
    float ss = p;
#pragma unroll
    for (int off = 32; off > 0; off >>= 1) ss += __shfl_xor(ss, off, 64);
    if (lane == 0) sh_red[8 + wave] = ss;
    __syncthreads();
    float tot = 0.f;
#pragma unroll
    for (int i = 0; i < 8; ++i) tot += sh_red[8 + i];
    sh_alpha[tid] = p / tot;
    __syncthreads();
    int ci = tid & 63, sid = tid >> 6;
    int col = cc * 128 + ci * 2;
    float ax = 0.f, ay = 0.f;
    for (int s = sid; s < 512; s += 8) {
        float a = sh_alpha[s];
        ushort2 xv = *(const ushort2*)(xb + ((size_t)(b * 512 + s) << 9) + col);
        ax += a * bf2f(xv.x);
        ay += a * bf2f(xv.y);
    }
    shp[sid][ci] = make_float2(ax, ay);
    __syncthreads();
    if (tid < 64) {
        float sx = 0.f, sy = 0.f;
#pragma unroll
        for (int r = 0; r < 8; ++r) { sx += shp[r][tid].x; sy += shp[r][tid].y; }
        ushort2 o; o.x = f2bf(sx); o.y = f2bf(sy);
        *(ushort2*)(inp + b * 1024 + cc * 128 + tid * 2) = o;
    }
}

// ---------------- gates: z -> (h,c,hs, inp h-part) ----------------
__global__ __launch_bounds__(512) void gates_kernel(
    const float* __restrict__ z, const int* __restrict__ text,
    const float* __restrict__ Wl, const float* __restrict__ bl,
    float* __restrict__ c, float* __restrict__ h,
    float* __restrict__ hs_t, unsigned short* __restrict__ inp, int t) {
    int b = blockIdx.x, hh = threadIdx.x;
    int ch = text[b * TEXTW + t];
    const float* wrow = Wl + (size_t)(512 + ch) * 2048;
    float4 zv = *(const float4*)(z + (size_t)b * 2048 + hh * 4);
    float zi = zv.x + bl[hh] + wrow[hh];
    float zf = zv.y + bl[512 + hh] + wrow[512 + hh];
    float zg = zv.z + bl[1024 + hh] + wrow[1024 + hh];
    float zo = zv.w + bl[1536 + hh] + wrow[1536 + hh];
    float ig = fast_sigmoid(zi);
    float fg = fast_sigmoid(zf);
    float gg = fast_tanh(zg);
    float og = fast_sigmoid(zo);
    int idx = b * 512 + hh;
    float cn = fg * c[idx] + ig * gg;
    float hn = og * fast_tanh(cn);
    c[idx] = cn;
    h[idx] = hn;
    hs_t[idx] = hn;
    inp[b * 1024 + 512 + hh] = f2bf(hn);
}

// ---------------- hp = h @ W_h2h + b_h2h (for next step) ----------------
// grid (jc=4, b=128), 256 threads: 64 j-pairs x 4-way k-split
__global__ __launch_bounds__(256) void hp_kernel(
    const float* __restrict__ h, const unsigned short* __restrict__ Whb,
    const float* __restrict__ bh2h, float* __restrict__ hp) {
    __shared__ float sh_h[512];
    __shared__ float2 shp[4][64];
    int b = blockIdx.y, jc = blockIdx.x;
    int tid = threadIdx.x;
    sh_h[tid] = h[b * 512 + tid];
    sh_h[256 + tid] = h[b * 512 + 256 + tid];
    __syncthreads();
    int j2 = tid & 63, kp = tid >> 6;
    int col = jc * 128 + j2 * 2;
    float ax = 0.f, ay = 0.f;
    for (int k = kp * 128; k < kp * 128 + 128; ++k) {
        float hv = sh_h[k];
        ushort2 w = *(const ushort2*)(Whb + k * 512 + col);
        ax += hv * bf2f(w.x);
        ay += hv * bf2f(w.y);
    }
    shp[kp][j2] = make_float2(ax, ay);
    __syncthreads();
    if (tid < 64) {
        float sx = bh2h[jc * 128 + tid * 2];
        float sy = bh2h[jc * 128 + tid * 2 + 1];
#pragma unroll
        for (int r = 0; r < 4; ++r) { sx += shp[r][tid].x; sy += shp[r][tid].y; }
        *(float2*)(hp + b * 512 + jc * 128 + tid * 2) = make_float2(sx, sy);
    }
}

// ---------------- probs = hs @ W_gen + b_gen ----------------
__global__ __launch_bounds__(64) void gen_probs(const float* __restrict__ hs,
                                                const float* __restrict__ Wg,
                                                const float* __restrict__ bg,
                                                float* __restrict__ out) {
    __shared__ float sh[512];
    int bt = blockIdx.x;
    int b = bt / T_, t = bt % T_;
    int tid = threadIdx.x;
    const float* hrow = hs + ((size_t)t * B_ + b) * H_;
    for (int i = tid; i < 512; i += 64) sh[i] = hrow[i];
    __syncthreads();
    float acc = bg[tid];
#pragma unroll 4
    for (int k = 0; k < 512; ++k) acc += sh[k] * Wg[k * 64 + tid];
    out[(size_t)bt * 64 + tid] = acc;
}

extern "C" void kernel_launch(void* const* d_in, const int* in_sizes, int n_in,
                              void* d_out, int out_size, void* d_ws, size_t ws_size,
                              hipStream_t stream) {
    const float* x       = (const float*)d_in[0];
    const int*   text    = (const int*)d_in[1];
    const float* W_i2h   = (const float*)d_in[2];
    const float* W_h2h   = (const float*)d_in[3];
    const float* b_h2h   = (const float*)d_in[4];
    const float* W_score = (const float*)d_in[5];
    const float* W_lstm  = (const float*)d_in[6];
    const float* U_lstm  = (const float*)d_in[7];
    const float* b_lstm  = (const float*)d_in[8];
    const float* W_gen   = (const float*)d_in[9];
    const float* b_gen   = (const float*)d_in[10];
    float* out = (float*)d_out;

    char* ws = (char*)d_ws;
    unsigned short* x_bf    = (unsigned short*)ws;                 // 67,108,864
    unsigned short* proj_bf = (unsigned short*)(ws + 67108864);    // 67,108,864
    unsigned short* Wt_bf   = (unsigned short*)(ws + 134217728);   //    524,288
    unsigned short* Wh_bf   = (unsigned short*)(ws + 134742016);   //    524,288
    unsigned short* WU_t    = (unsigned short*)(ws + 135266304);   //  4,194,304
    float* h       = (float*)(ws + 139460608);                     //    262,144
    float* c       = (float*)(ws + 139722752);                     //    262,144
    float* hp_buf  = (float*)(ws + 139984896);                     //    262,144
    float* e_buf   = (float*)(ws + 140247040);                     //    262,144
    unsigned short* inp_bf = (unsigned short*)(ws + 140509184);    //    262,144
    float* z_buf   = (float*)(ws + 140771328);                     //  1,048,576
    float* hs      = (float*)(ws + 141819904);                     // 13,107,200 -> end 154,927,104

    init_k<<<dim3(128), 512, 0, stream>>>(h, c, hp_buf, b_h2h, inp_bf);
    conv_x<<<dim3(32768), 256, 0, stream>>>(x, x_bf);
    conv_wt<<<dim3(512), 512, 0, stream>>>(W_i2h, Wt_bf);
    conv_wh<<<dim3(512), 512, 0, stream>>>(W_h2h, Wh_bf);
    conv_wut<<<dim3(2048), 256, 0, stream>>>(W_lstm, U_lstm, WU_t);
    gemm_proj<<<dim3(4, 512), 256, 0, stream>>>(x_bf, Wt_bf, proj_bf);
    for (int t = 0; t < T_; ++t) {
        e_kernel<<<dim3(8, 128), 256, 0, stream>>>(proj_bf, hp_buf, W_score, e_buf);
        ctx_kernel<<<dim3(4, 128), 512, 0, stream>>>(e_buf, x_bf, inp_bf);
        z_gemm<<<dim3(16), 256, 0, stream>>>(inp_bf, WU_t, z_buf);
        gates_kernel<<<dim3(128), 512, 0, stream>>>(z_buf, text, W_lstm, b_lstm,
                                                    c, h, hs + (size_t)t * (B_ * H_), inp_bf, t);
        if (t < T_ - 1)
            hp_kernel<<<dim3(4, 128), 256, 0, stream>>>(h, Wh_bf, b_h2h, hp_buf);
    }
    gen_probs<<<dim3(B_ * T_), 64, 0, stream>>>(hs, W_gen, b_gen, out);
}